// Round 1
// baseline (571.147 us; speedup 1.0000x reference)
//
#include <hip/hip_runtime.h>
#include <math.h>

typedef short v8s __attribute__((ext_vector_type(8)));
typedef short v4s __attribute__((ext_vector_type(4)));
typedef float v4f __attribute__((ext_vector_type(4)));

__device__ __forceinline__ float b2f(unsigned short u) {
    return __uint_as_float(((unsigned)u) << 16);
}
__device__ __forceinline__ unsigned short f2b(float f) {
    unsigned u = __float_as_uint(f);
    unsigned r = (u + 0x7FFF + ((u >> 16) & 1)) >> 16;
    return (unsigned short)r;
}

// async global->LDS, 16B per lane; lds dest is wave-uniform base + lane*16
__device__ __forceinline__ void gl_lds16(const unsigned short* g, unsigned short* l) {
    __builtin_amdgcn_global_load_lds(
        (const __attribute__((address_space(1))) void*)g,
        (__attribute__((address_space(3))) void*)l,
        16, 0, 0);
}

// ---------------- zero fill ----------------
__global__ __launch_bounds__(256) void zero_fill(float* __restrict__ p, int n) {
    int i = blockIdx.x * 256 + threadIdx.x;
    if (i < n) p[i] = 0.0f;
}

// ---------------- LN1 fused: fp32 x -> bf16 normed ----------------
__global__ __launch_bounds__(256) void ln_apply(const float* __restrict__ x,
                                                const float* __restrict__ g,
                                                const float* __restrict__ bt,
                                                unsigned short* __restrict__ out) {
    size_t row = blockIdx.x;
    const float* p = x + row * 512;
    int t = threadIdx.x;
    float v0 = p[t];
    float v1 = p[t + 256];
    float s = v0 + v1, s2 = v0 * v0 + v1 * v1;
    for (int o = 32; o > 0; o >>= 1) {
        s += __shfl_down(s, o);
        s2 += __shfl_down(s2, o);
    }
    __shared__ float rs[4], rq[4];
    int wave = t >> 6, lane = t & 63;
    if (lane == 0) { rs[wave] = s; rq[wave] = s2; }
    __syncthreads();
    float ts = rs[0] + rs[1] + rs[2] + rs[3];
    float tq = rq[0] + rq[1] + rq[2] + rq[3];
    float mean = ts * (1.0f / 512.0f);
    float var = tq * (1.0f / 512.0f) - mean * mean;
    float inv = rsqrtf(var + 1e-5f);
    unsigned short* o0 = out + row * 512;
    o0[t]       = f2b((v0 - mean) * inv * g[t]       + bt[t]);
    o0[t + 256] = f2b((v1 - mean) * inv * g[t + 256] + bt[t + 256]);
}

// ---------------- LayerNorm: bf16 in -> bf16 out, fp32 gamma/beta (LN2) ----------------
__global__ __launch_bounds__(256) void ln_bf16_kernel(const unsigned short* __restrict__ in,
                                                      const float* __restrict__ g,
                                                      const float* __restrict__ bt,
                                                      unsigned short* __restrict__ out) {
    size_t row = blockIdx.x;
    const unsigned short* p = in + row * 512;
    int t = threadIdx.x;
    float v0 = b2f(p[t]);
    float v1 = b2f(p[t + 256]);
    float s = v0 + v1, s2 = v0 * v0 + v1 * v1;
    for (int o = 32; o > 0; o >>= 1) {
        s += __shfl_down(s, o);
        s2 += __shfl_down(s2, o);
    }
    __shared__ float rs[4], rq[4];
    int wave = t >> 6, lane = t & 63;
    if (lane == 0) { rs[wave] = s; rq[wave] = s2; }
    __syncthreads();
    float ts = rs[0] + rs[1] + rs[2] + rs[3];
    float tq = rq[0] + rq[1] + rq[2] + rq[3];
    float mean = ts * (1.0f / 512.0f);
    float var = tq * (1.0f / 512.0f) - mean * mean;
    float inv = rsqrtf(var + 1e-5f);
    unsigned short* o0 = out + row * 512;
    o0[t]       = f2b((v0 - mean) * inv * g[t]       + bt[t]);
    o0[t + 256] = f2b((v1 - mean) * inv * g[t + 256] + bt[t + 256]);
}

// ---------------- weight transpose + fp32->bf16 ----------------
__global__ __launch_bounds__(256) void transpose_f2b(const float* __restrict__ in,
                                                     unsigned short* __restrict__ out,
                                                     int R, int C) {
    __shared__ unsigned short tile[32][33];
    int c0 = blockIdx.x * 32, r0 = blockIdx.y * 32;
    int tx = threadIdx.x, ty = threadIdx.y;
    for (int j = 0; j < 32; j += 8)
        tile[ty + j][tx] = f2b(in[(size_t)(r0 + ty + j) * C + c0 + tx]);
    __syncthreads();
    for (int j = 0; j < 32; j += 8)
        out[(size_t)(c0 + ty + j) * R + r0 + tx] = tile[tx][ty + j];
}

// ---------------- tiled bf16 transpose ----------------
__global__ __launch_bounds__(256) void transpose_bf16(const unsigned short* __restrict__ in,
                                                      unsigned short* __restrict__ out,
                                                      int R, int C) {
    __shared__ unsigned short tile[32][33];
    size_t boff = (size_t)blockIdx.z * R * C;
    int c0 = blockIdx.x * 32, r0 = blockIdx.y * 32;
    int tx = threadIdx.x, ty = threadIdx.y;
    for (int j = 0; j < 32; j += 8)
        tile[ty + j][tx] = in[boff + (size_t)(r0 + ty + j) * C + c0 + tx];
    __syncthreads();
    for (int j = 0; j < 32; j += 8)
        out[boff + (size_t)(c0 + ty + j) * R + r0 + tx] = tile[tx][ty + j];
}

// ================================================================================
// 256x256-tile GEMM, K=512 (NKT=16 K-tiles of BK=32), 8 waves (2Mx4N), 512 threads.
// 4-deep LDS K-tile ring (4 x (16KB A + 16KB B) = 128KB) with counted vmcnt:
//   - each thread issues exactly 4 global_load_lds per K-tile (2 A granules, 2 B)
//   - loads for tile t+2 are issued during tile t (slot (t+2)&3 was last read at
//     t-2, two barriers earlier -> no clobber race)
//   - at tile-t top: s_waitcnt vmcnt(4) retires exactly tile t's loads (FIFO),
//     keeping tile t+1's 4 loads in flight; vmcnt(0) only on the final tile
//   - one raw s_barrier per K-tile (after the waitcnt), memory-clobber fenced
// T2 read-swizzle (both-sides, rule #21): granule position p = c ^ ((row>>1)&3)
// applied to the GLOBAL source address (LDS dest stays linear for gl_lds) and to
// the ds_read address: every aligned 8-lane group covers all 8 bank-granule
// slots exactly once -> conflict-free ds_read_b128.
// T1: bijective XCD-chunked block swizzle (grid % 8 == 0 for both instances).
// T5: setprio(1) around the 32-MFMA cluster.
// ================================================================================
template <int NB, bool QKV>
__global__ __launch_bounds__(512, 2) void gemm256(const unsigned short* __restrict__ A,
                                                  const unsigned short* __restrict__ Bt,
                                                  const float* __restrict__ bias,
                                                  unsigned short* __restrict__ o0,
                                                  unsigned short* __restrict__ o1,
                                                  unsigned short* __restrict__ o2) {
    __shared__ __align__(16) unsigned short As[4][256 * 32];
    __shared__ __align__(16) unsigned short Bs[4][256 * 32];
    int t = threadIdx.x;
    int wave = t >> 6, lane = t & 63;
    int wm = wave >> 2, wn = wave & 3;           // 2 M-halves x 4 N-quarters
    int mrow = lane & 15, kq4 = lane >> 4;
    // XCD-aware bijective chunked swizzle (gridDim.x % 8 == 0)
    int nwg = gridDim.x;
    int cpx = nwg >> 3;
    int bid = blockIdx.x;
    int swz = (bid & 7) * cpx + (bid >> 3);
    int n0 = (swz % NB) * 256;
    int m0 = (swz / NB) * 256;
    const unsigned short* Ab = A + (size_t)m0 * 512;
    const unsigned short* Bb = Bt + (size_t)n0 * 512;
    // staging geometry: granule g in [0,1024) -> row r = g>>2, swizzled source
    // granule c = (g&3) ^ ((r>>1)&3). LDS dest is linear (wave-uniform base +
    // lane*16), so the swizzle is applied on the global source side.
    int g0 = wave * 128 + lane;
    int g1 = g0 + 64;
    int r0 = g0 >> 2, c0 = ((g0 & 3) ^ ((r0 >> 1) & 3)) * 8;
    int r1 = g1 >> 2, c1 = ((g1 & 3) ^ ((r1 >> 1) & 3)) * 8;
    size_t src0 = (size_t)r0 * 512 + c0;
    size_t src1 = (size_t)r1 * 512 + c1;
    unsigned ldsOff0 = wave * 1024;              // shorts (granule g0 base)
    unsigned ldsOff1 = wave * 1024 + 512;        // shorts (granule g1 base)
    v4f acc[8][4] = {};
    // fragment read swizzle: (row>>1)&3 == ((row&15)>>1)&3 since 16-aligned bases
    int swr = ((kq4 ^ ((mrow >> 1) & 3)) * 8);

#define STAGE(kt, slot)                                          \
    do {                                                         \
        const unsigned short* aS = Ab + (size_t)(kt) * 32;       \
        const unsigned short* bS = Bb + (size_t)(kt) * 32;       \
        gl_lds16(aS + src0, &As[slot][ldsOff0]);                 \
        gl_lds16(aS + src1, &As[slot][ldsOff1]);                 \
        gl_lds16(bS + src0, &Bs[slot][ldsOff0]);                 \
        gl_lds16(bS + src1, &Bs[slot][ldsOff1]);                 \
    } while (0)

    STAGE(0, 0);
    STAGE(1, 1);
    for (int kt = 0; kt < 16; ++kt) {
        if (kt < 15) {
            asm volatile("s_waitcnt vmcnt(4)" ::: "memory");
        } else {
            asm volatile("s_waitcnt vmcnt(0)" ::: "memory");
        }
        __builtin_amdgcn_s_barrier();
        asm volatile("" ::: "memory");
        if (kt + 2 < 16) {
            int slot2 = (kt + 2) & 3;
            STAGE(kt + 2, slot2);
        }
        const unsigned short* as = As[kt & 3];
        const unsigned short* bs = Bs[kt & 3];
        v8s af[8], bf[4];
#pragma unroll
        for (int i = 0; i < 8; i++)
            af[i] = *(const v8s*)&as[(wm * 128 + i * 16 + mrow) * 32 + swr];
#pragma unroll
        for (int j = 0; j < 4; j++)
            bf[j] = *(const v8s*)&bs[(wn * 64 + j * 16 + mrow) * 32 + swr];
        __builtin_amdgcn_s_setprio(1);
#pragma unroll
        for (int i = 0; i < 8; i++)
#pragma unroll
            for (int j = 0; j < 4; j++)
                acc[i][j] = __builtin_amdgcn_mfma_f32_16x16x32_bf16(af[i], bf[j], acc[i][j], 0, 0, 0);
        __builtin_amdgcn_s_setprio(0);
    }
#undef STAGE
    // epilogue: C[row][col], col = lane&15 (+16j), row = (lane>>4)*4 + r (+16i)
#pragma unroll
    for (int j = 0; j < 4; j++) {
        int col = n0 + wn * 64 + j * 16 + mrow;
        float bv = bias[col];
        unsigned short* base;
        int c;
        bool doRelu;
        if (QKV) {
            int seg = col >> 9;
            c = col & 511;
            base = (seg == 0) ? o0 : ((seg == 1) ? o1 : o2);
            doRelu = col < 1024;
        } else {
            base = o0;
            c = col;
            doRelu = false;
        }
#pragma unroll
        for (int i = 0; i < 8; i++) {
            int row = m0 + wm * 128 + i * 16 + kq4 * 4;
#pragma unroll
            for (int r = 0; r < 4; r++) {
                float v = acc[i][j][r] + bv;
                if (doRelu) v = fmaxf(v, 0.0f);
                base[(size_t)(row + r) * 512 + c] = f2b(v);
            }
        }
    }
}

// ---------------- kv partials: per (bh, chunk of 128 rows), no atomics ----------------
__global__ __launch_bounds__(256) void kv_part(const unsigned short* __restrict__ kbuf,
                                               const unsigned short* __restrict__ vbuf,
                                               float* __restrict__ kvp,
                                               float* __restrict__ ksp) {
    int bh = blockIdx.x;   // 0..63
    int b = bh >> 3, h = bh & 7;
    int nc = blockIdx.y;   // 0..31
    __shared__ __align__(16) unsigned short kb[64 * 64];
    __shared__ __align__(16) unsigned short vb[64 * 64];
    int t = threadIdx.x;
    int dk0 = (t >> 4) * 4;
    int dv0 = (t & 15) * 4;
    float acc[4][4] = {};
    float ks[4] = {};
    int lr = t >> 2, lc = (t & 3) * 16;
    for (int n0 = nc * 128; n0 < nc * 128 + 128; n0 += 64) {
        __syncthreads();
        size_t base = ((size_t)(b * 4096 + n0 + lr)) * 512 + h * 64;
        *(v8s*)&kb[lr * 64 + lc]     = *(const v8s*)&kbuf[base + lc];
        *(v8s*)&kb[lr * 64 + lc + 8] = *(const v8s*)&kbuf[base + lc + 8];
        *(v8s*)&vb[lr * 64 + lc]     = *(const v8s*)&vbuf[base + lc];
        *(v8s*)&vb[lr * 64 + lc + 8] = *(const v8s*)&vbuf[base + lc + 8];
        __syncthreads();
#pragma unroll 4
        for (int nn = 0; nn < 64; nn++) {
            v4s kr = *(const v4s*)&kb[nn * 64 + dk0];
            v4s vr = *(const v4s*)&vb[nn * 64 + dv0];
            float kf[4], vf[4];
#pragma unroll
            for (int i = 0; i < 4; i++) { kf[i] = b2f((unsigned short)kr[i]); vf[i] = b2f((unsigned short)vr[i]); }
#pragma unroll
            for (int i = 0; i < 4; i++) {
#pragma unroll
                for (int j = 0; j < 4; j++) acc[i][j] += kf[i] * vf[j];
            }
            if ((t & 15) == 0) {
#pragma unroll
                for (int i = 0; i < 4; i++) ks[i] += kf[i];
            }
        }
    }
    float* dst = kvp + ((size_t)(bh * 32 + nc)) * 4096;
#pragma unroll
    for (int i = 0; i < 4; i++)
        *(float4*)&dst[(dk0 + i) * 64 + dv0] = make_float4(acc[i][0], acc[i][1], acc[i][2], acc[i][3]);
    if ((t & 15) == 0) {
        float* kd = ksp + ((size_t)(bh * 32 + nc)) * 64;
#pragma unroll
        for (int i = 0; i < 4; i++) kd[dk0 + i] = ks[i];
    }
}

// ---------------- kv reduce: sum 32 partials -> kvb, ksum ----------------
__global__ __launch_bounds__(256) void kv_reduce(const float* __restrict__ kvp,
                                                 const float* __restrict__ ksp,
                                                 float* __restrict__ kvb,
                                                 float* __restrict__ ksum) {
    int tid = blockIdx.x * 256 + threadIdx.x;
    int bh = tid >> 12, e = tid & 4095;
    float s = 0.0f;
#pragma unroll 8
    for (int c = 0; c < 32; c++) s += kvp[((size_t)(bh * 32 + c)) * 4096 + e];
    kvb[(size_t)bh * 4096 + e] = s;
    if (tid < 4096) {
        int bh2 = tid >> 6, dk = tid & 63;
        float t = 0.0f;
#pragma unroll 8
        for (int c = 0; c < 32; c++) t += ksp[((size_t)(bh2 * 32 + c)) * 64 + dk];
        ksum[tid] = t;
    }
}

// ---------------- attn; IN-PLACE over q ----------------
__global__ __launch_bounds__(256) void attn_kernel(unsigned short* qa,
                                                   const float* __restrict__ kv,
                                                   const float* __restrict__ ksum) {
    int bh = blockIdx.y;
    int b = bh >> 3, h = bh & 7;
    int nt = blockIdx.x;
    __shared__ float kvs[64 * 64];
    __shared__ float nrm[64];
    int t = threadIdx.x;
    for (int i = t; i < 4096; i += 256) kvs[i] = kv[(size_t)bh * 4096 + i];
    if (t < 64) nrm[t] = fmaxf(ksum[bh * 64 + t], 100.0f);
    __syncthreads();
    int n = nt * 256 + t;
    unsigned short* qp = qa + ((size_t)(b * 4096 + n)) * 512 + h * 64;
    float qf[64];
#pragma unroll
    for (int i = 0; i < 64; i += 8) {
        v8s v = *(const v8s*)&qp[i];
#pragma unroll
        for (int j = 0; j < 8; j++) qf[i + j] = b2f((unsigned short)v[j]);
    }
    float denom = 0.0f;
#pragma unroll
    for (int d = 0; d < 64; d++) denom += qf[d] * nrm[d];
    denom = fmaxf(denom, 100.0f);
    float inv = 1.0f / denom;
#pragma unroll
    for (int dv = 0; dv < 64; dv += 16) {
        float o[16] = {};
        for (int dk = 0; dk < 64; dk++) {
            float q = qf[dk];
#pragma unroll
            for (int i = 0; i < 16; i++) o[i] += q * kvs[dk * 64 + dv + i];
        }
#pragma unroll
        for (int i = 0; i < 16; i++) qp[dv + i] = f2b(o[i] * inv);
    }
}

// ---------------- depthwise conv 7x7 + GELU + BN stats; column-sliding ----------
__global__ __launch_bounds__(256) void dwconv7_gelu(const unsigned short* __restrict__ in,
                                                    const float* __restrict__ w,
                                                    const float* __restrict__ bias,
                                                    unsigned short* __restrict__ out,
                                                    float* __restrict__ bn_sum,
                                                    float* __restrict__ bn_sumsq) {
    int bc = blockIdx.x;
    int c = bc & 511;
    __shared__ float img[70 * 72];
    __shared__ float wsm[49];
    __shared__ float r1[4], r2[4];
    int t = threadIdx.x;
    int tx = t & 63, ty = t >> 6;
    for (int i = t; i < 70 * 72; i += 256) img[i] = 0.0f;
    if (t < 49) wsm[t] = w[c * 49 + t];
    __syncthreads();
    const unsigned short* src = in + (size_t)bc * 4096;
    for (int p = t; p < 4096; p += 256)
        img[((p >> 6) + 3) * 72 + (p & 63) + 3] = b2f(src[p]);
    __syncthreads();
    float wt[49];
#pragma unroll
    for (int i = 0; i < 49; i++) wt[i] = wsm[i];
    float bv = bias[c];
    float acc[16];
#pragma unroll
    for (int i = 0; i < 16; i++) acc[i] = bv;
    int h0 = ty * 16;
#pragma unroll
    for (int rr = 0; rr < 22; rr++) {
        float v[7];
#pragma unroll
        for (int kw = 0; kw < 7; kw++) v[kw] = img[(h0 + rr) * 72 + tx + kw];
#pragma unroll
        for (int kh = 0; kh < 7; kh++) {
            int o = rr - kh;
            if (o >= 0 && o <= 15) {
                float dot = v[0] * wt[kh * 7];
#pragma unroll
                for (int kw = 1; kw < 7; kw++) dot += v[kw] * wt[kh * 7 + kw];
                acc[o] += dot;
            }
        }
    }
    float s = 0.0f, s2 = 0.0f;
    unsigned short* dst = out + (size_t)bc * 4096;
#pragma unroll
    for (int i = 0; i < 16; i++) {
        float a = acc[i];
        float ge = 0.5f * a * (1.0f + erff(a * 0.70710678118f));
        dst[(h0 + i) * 64 + tx] = f2b(ge);
        s += ge;
        s2 += ge * ge;
    }
    for (int o = 32; o > 0; o >>= 1) {
        s += __shfl_down(s, o);
        s2 += __shfl_down(s2, o);
    }
    int lane = t & 63;
    if (lane == 0) { r1[ty] = s; r2[ty] = s2; }
    __syncthreads();
    if (t == 0) {
        atomicAdd(&bn_sum[c], r1[0] + r1[1] + r1[2] + r1[3]);
        atomicAdd(&bn_sumsq[c], r2[0] + r2[1] + r2[2] + r2[3]);
    }
}

__global__ void bn_finalize(const float* __restrict__ s, const float* __restrict__ s2,
                            const float* __restrict__ g, const float* __restrict__ b,
                            float2* __restrict__ ab) {
    int c = blockIdx.x * blockDim.x + threadIdx.x;
    if (c >= 512) return;
    float m = s[c] * (1.0f / 32768.0f);
    float var = s2[c] * (1.0f / 32768.0f) - m * m;
    float inv = rsqrtf(var + 1e-5f);
    float sc = g[c] * inv;
    ab[c] = make_float2(sc, b[c] - m * sc);
}

// ---------------- depthwise conv 7x7 with BN affine on load; column-sliding -------------------
__global__ __launch_bounds__(256) void dwconv7_bn(const unsigned short* __restrict__ in,
                                                  const float2* __restrict__ bnab,
                                                  const float* __restrict__ w,
                                                  const float* __restrict__ bias,
                                                  unsigned short* __restrict__ out) {
    int bc = blockIdx.x;
    int c = bc & 511;
    __shared__ float img[70 * 72];
    __shared__ float wsm[49];
    int t = threadIdx.x;
    int tx = t & 63, ty = t >> 6;
    for (int i = t; i < 70 * 72; i += 256) img[i] = 0.0f;
    if (t < 49) wsm[t] = w[c * 49 + t];
    __syncthreads();
    float2 ab = bnab[c];
    const unsigned short* src = in + (size_t)bc * 4096;
    for (int p = t; p < 4096; p += 256)
        img[((p >> 6) + 3) * 72 + (p & 63) + 3] = b2f(src[p]) * ab.x + ab.y;
    __syncthreads();
    float wt[49];
#pragma unroll
    for (int i = 0; i < 49; i++) wt[i] = wsm[i];
    float bv = bias[c];
    float acc[16];
#pragma unroll
    for (int i = 0; i < 16; i++) acc[i] = bv;
    int h0 = ty * 16;
#pragma unroll
    for (int rr = 0; rr < 22; rr++) {
        float v[7];
#pragma unroll
        for (int kw = 0; kw < 7; kw++) v[kw] = img[(h0 + rr) * 72 + tx + kw];
#pragma unroll
        for (int kh = 0; kh < 7; kh++) {
            int o = rr - kh;
            if (o >= 0 && o <= 15) {
                float dot = v[0] * wt[kh * 7];
#pragma unroll
                for (int kw = 1; kw < 7; kw++) dot += v[kw] * wt[kh * 7 + kw];
                acc[o] += dot;
            }
        }
    }
    unsigned short* dst = out + (size_t)bc * 4096;
#pragma unroll
    for (int i = 0; i < 16; i++)
        dst[(h0 + i) * 64 + tx] = f2b(acc[i]);
}

// ---------------- final: out = x(f32) + attn(bf16) + y2^T(bf16) -> f32 ----------------
__global__ __launch_bounds__(256) void final_add(const float* __restrict__ x,
                                                 const unsigned short* __restrict__ attn,
                                                 const unsigned short* __restrict__ y2,
                                                 float* __restrict__ out) {
    __shared__ unsigned short tile[32][33];
    int b = blockIdx.z;
    int c0 = blockIdx.x * 32, n0 = blockIdx.y * 32;
    int tx = threadIdx.x, ty = threadIdx.y;
    for (int j = 0; j < 32; j += 8)
        tile[ty + j][tx] = y2[((size_t)(b * 512 + c0 + ty + j)) * 4096 + n0 + tx];
    __syncthreads();
    for (int j = 0; j < 32; j += 8) {
        int n = n0 + ty + j, cc = c0 + tx;
        size_t idx = ((size_t)(b * 4096 + n)) * 512 + cc;
        out[idx] = x[idx] + b2f(attn[idx]) + b2f(tile[tx][ty + j]);
    }
}

// ------------------------------------------------------------------------------------------------
extern "C" void kernel_launch(void* const* d_in, const int* in_sizes, int n_in,
                              void* d_out, int out_size, void* d_ws, size_t ws_size,
                              hipStream_t stream) {
    const float* x     = (const float*)d_in[0];
    const float* qkv_w = (const float*)d_in[1];
    const float* qkv_b = (const float*)d_in[2];
    const float* out_w = (const float*)d_in[3];
    const float* out_b = (const float*)d_in[4];
    const float* pre_g = (const float*)d_in[5];
    const float* pre_b = (const float*)d_in[6];
    const float* lcm_g = (const float*)d_in[7];
    const float* lcm_b = (const float*)d_in[8];
    const float* ci_w  = (const float*)d_in[9];
    const float* ci_b  = (const float*)d_in[10];
    const float* bn_g  = (const float*)d_in[11];
    const float* bn_b  = (const float*)d_in[12];
    const float* co_w  = (const float*)d_in[13];
    const float* co_b  = (const float*)d_in[14];

    char* ws = (char*)d_ws;
    const size_t SLOT = 33554432;  // 32768*512*2 bytes (bf16)
    unsigned short* S0 = (unsigned short*)(ws);               // q -> attn -> xi -> y2
    unsigned short* S1 = (unsigned short*)(ws + SLOT);        // k -> attn_out(bf16)
    unsigned short* S2 = (unsigned short*)(ws + 2 * SLOT);    // v -> t -> y
    const size_t MISC = 3 * SLOT;                             // 96MB
    unsigned short* wT1 = (unsigned short*)(ws + MISC);                 // 1.5MB bf16
    unsigned short* wT2 = (unsigned short*)(ws + MISC + 1572864);       // 0.5MB bf16
    float* kvb          = (float*)(ws + MISC + 2097152);                // 1MB
    float* ksum         = (float*)(ws + MISC + 2097152 + 1048576);      // 16KB
    float* bn_sum       = (float*)(ws + MISC + 2097152 + 1048576 + 16384);        // 2KB
    float* bn_sumsq     = (float*)(ws + MISC + 2097152 + 1048576 + 16384 + 2048); // 2KB
    float2* bnab        = (float2*)(ws + MISC + 3166208);               // 4KB
    float* ksp          = (float*)(ws + MISC + 3170304);                // 512KB
    float* outp         = (float*)d_out;

    // d_out doubles as scratch before final_add fully overwrites it:
    unsigned short* normed = (unsigned short*)d_out;                    // 32MB bf16
    float* kvp             = (float*)((char*)d_out + SLOT);             // 32MB fp32 partials

    dim3 tb(32, 8);
    transpose_f2b<<<dim3(48, 16), tb, 0, stream>>>(qkv_w, wT1, 512, 1536);
    transpose_f2b<<<dim3(16, 16), tb, 0, stream>>>(out_w, wT2, 512, 512);
    zero_fill<<<4, 256, 0, stream>>>(bn_sum, 1024);  // bn_sum + bn_sumsq
    ln_apply<<<32768, 256, 0, stream>>>(x, pre_g, pre_b, normed);
    // M=32768, N=1536 -> 128 x 6 = 768 blocks (768 % 8 == 0)
    gemm256<6, true><<<768, 512, 0, stream>>>(normed, wT1, qkv_b, S0, S1, S2);
    kv_part<<<dim3(64, 32), 256, 0, stream>>>(S1, S2, kvp, ksp);
    kv_reduce<<<1024, 256, 0, stream>>>(kvp, ksp, kvb, ksum);
    attn_kernel<<<dim3(16, 64), 256, 0, stream>>>(S0, kvb, ksum);
    // M=32768, N=512 -> 128 x 2 = 256 blocks (256 % 8 == 0)
    gemm256<2, false><<<256, 512, 0, stream>>>(S0, wT2, out_b, S1, S1, S1);
    ln_bf16_kernel<<<32768, 256, 0, stream>>>(S1, lcm_g, lcm_b, S2);
    transpose_bf16<<<dim3(16, 128, 8), tb, 0, stream>>>(S2, S0, 4096, 512);
    dwconv7_gelu<<<4096, 256, 0, stream>>>(S0, ci_w, ci_b, S2, bn_sum, bn_sumsq);
    bn_finalize<<<2, 256, 0, stream>>>(bn_sum, bn_sumsq, bn_g, bn_b, bnab);
    dwconv7_bn<<<4096, 256, 0, stream>>>(S2, bnab, co_w, co_b, S0);
    final_add<<<dim3(16, 128, 8), tb, 0, stream>>>(x, S1, S0, outp);
}

// Round 2
// 515.829 us; speedup vs baseline: 1.1072x; 1.1072x over previous
//
#include <hip/hip_runtime.h>
#include <math.h>

typedef short v8s __attribute__((ext_vector_type(8)));
typedef short v4s __attribute__((ext_vector_type(4)));
typedef float v4f __attribute__((ext_vector_type(4)));

__device__ __forceinline__ float b2f(unsigned short u) {
    return __uint_as_float(((unsigned)u) << 16);
}
__device__ __forceinline__ unsigned short f2b(float f) {
    unsigned u = __float_as_uint(f);
    unsigned r = (u + 0x7FFF + ((u >> 16) & 1)) >> 16;
    return (unsigned short)r;
}

// async global->LDS, 16B per lane; lds dest is wave-uniform base + lane*16
__device__ __forceinline__ void gl_lds16(const unsigned short* g, unsigned short* l) {
    __builtin_amdgcn_global_load_lds(
        (const __attribute__((address_space(1))) void*)g,
        (__attribute__((address_space(3))) void*)l,
        16, 0, 0);
}

// ---------------- zero fill ----------------
__global__ __launch_bounds__(256) void zero_fill(float* __restrict__ p, int n) {
    int i = blockIdx.x * 256 + threadIdx.x;
    if (i < n) p[i] = 0.0f;
}

// ---------------- LN1 fused: fp32 x -> bf16 normed (float2 vectorized) ----------------
__global__ __launch_bounds__(256) void ln_apply(const float* __restrict__ x,
                                                const float* __restrict__ g,
                                                const float* __restrict__ bt,
                                                unsigned short* __restrict__ out) {
    size_t row = blockIdx.x;
    const float2* p = (const float2*)(x + row * 512);
    int t = threadIdx.x;
    float2 v = p[t];
    float s = v.x + v.y, s2 = v.x * v.x + v.y * v.y;
    for (int o = 32; o > 0; o >>= 1) {
        s += __shfl_down(s, o);
        s2 += __shfl_down(s2, o);
    }
    __shared__ float rs[4], rq[4];
    int wave = t >> 6, lane = t & 63;
    if (lane == 0) { rs[wave] = s; rq[wave] = s2; }
    __syncthreads();
    float ts = rs[0] + rs[1] + rs[2] + rs[3];
    float tq = rq[0] + rq[1] + rq[2] + rq[3];
    float mean = ts * (1.0f / 512.0f);
    float var = tq * (1.0f / 512.0f) - mean * mean;
    float inv = rsqrtf(var + 1e-5f);
    float2 gg = ((const float2*)g)[t];
    float2 bb = ((const float2*)bt)[t];
    ushort2 o2;
    o2.x = f2b((v.x - mean) * inv * gg.x + bb.x);
    o2.y = f2b((v.y - mean) * inv * gg.y + bb.y);
    *(ushort2*)&out[row * 512 + 2 * t] = o2;
}

// ---------------- weight transpose + fp32->bf16 ----------------
__global__ __launch_bounds__(256) void transpose_f2b(const float* __restrict__ in,
                                                     unsigned short* __restrict__ out,
                                                     int R, int C) {
    __shared__ unsigned short tile[32][33];
    int c0 = blockIdx.x * 32, r0 = blockIdx.y * 32;
    int tx = threadIdx.x, ty = threadIdx.y;
    for (int j = 0; j < 32; j += 8)
        tile[ty + j][tx] = f2b(in[(size_t)(r0 + ty + j) * C + c0 + tx]);
    __syncthreads();
    for (int j = 0; j < 32; j += 8)
        out[(size_t)(c0 + ty + j) * R + r0 + tx] = tile[tx][ty + j];
}

// ================================================================================
// 256x256-tile GEMM, K=512 (16 K-tiles of BK=32), 8 waves (2Mx4N), 512 threads.
// 4-deep LDS K-tile ring with counted vmcnt (T3+T4), T2 both-sides swizzle on
// staging/fragment reads, T1 bijective XCD swizzle, T5 setprio around MFMA.
// NEW (r2): epilogue stages the 256x256 bf16 output tile through the (reused)
// ring LDS with a per-row granule-XOR layout, then streams it out with
// global_store_dwordx4 so every 128B line is written completely & contiguously
// (fixes the 1.84x WRITE_SIZE amplification of the scalar scattered epilogue).
// ================================================================================
template <int NB, bool QKV>
__global__ __launch_bounds__(512, 2) void gemm256(const unsigned short* __restrict__ A,
                                                  const unsigned short* __restrict__ Bt,
                                                  const float* __restrict__ bias,
                                                  unsigned short* __restrict__ o0,
                                                  unsigned short* __restrict__ o1,
                                                  unsigned short* __restrict__ o2) {
    __shared__ __align__(16) unsigned short LB[4][2][8192];  // [slot][A/B][256*32] = 128KB
    int t = threadIdx.x;
    int wave = t >> 6, lane = t & 63;
    int wm = wave >> 2, wn = wave & 3;           // 2 M-halves x 4 N-quarters
    int mrow = lane & 15, kq4 = lane >> 4;
    // XCD-aware bijective chunked swizzle (gridDim.x % 8 == 0)
    int nwg = gridDim.x;
    int cpx = nwg >> 3;
    int bid = blockIdx.x;
    int swz = (bid & 7) * cpx + (bid >> 3);
    int n0 = (swz % NB) * 256;
    int m0 = (swz / NB) * 256;
    const unsigned short* Ab = A + (size_t)m0 * 512;
    const unsigned short* Bb = Bt + (size_t)n0 * 512;
    // staging geometry: granule g in [0,1024) -> row r = g>>2, swizzled source
    // granule c = (g&3) ^ ((r>>1)&3). LDS dest is linear.
    int g0 = wave * 128 + lane;
    int g1 = g0 + 64;
    int r0 = g0 >> 2, c0 = ((g0 & 3) ^ ((r0 >> 1) & 3)) * 8;
    int r1 = g1 >> 2, c1 = ((g1 & 3) ^ ((r1 >> 1) & 3)) * 8;
    size_t src0 = (size_t)r0 * 512 + c0;
    size_t src1 = (size_t)r1 * 512 + c1;
    unsigned ldsOff0 = wave * 1024;
    unsigned ldsOff1 = wave * 1024 + 512;
    v4f acc[8][4] = {};
    // fragment read swizzle
    int swr = ((kq4 ^ ((mrow >> 1) & 3)) * 8);

#define STAGE(kt, slot)                                          \
    do {                                                         \
        const unsigned short* aS = Ab + (size_t)(kt) * 32;       \
        const unsigned short* bS = Bb + (size_t)(kt) * 32;       \
        gl_lds16(aS + src0, &LB[slot][0][ldsOff0]);              \
        gl_lds16(aS + src1, &LB[slot][0][ldsOff1]);              \
        gl_lds16(bS + src0, &LB[slot][1][ldsOff0]);              \
        gl_lds16(bS + src1, &LB[slot][1][ldsOff1]);              \
    } while (0)

    STAGE(0, 0);
    STAGE(1, 1);
    for (int kt = 0; kt < 16; ++kt) {
        if (kt < 15) {
            asm volatile("s_waitcnt vmcnt(4)" ::: "memory");
        } else {
            asm volatile("s_waitcnt vmcnt(0)" ::: "memory");
        }
        __builtin_amdgcn_s_barrier();
        asm volatile("" ::: "memory");
        if (kt + 2 < 16) {
            int slot2 = (kt + 2) & 3;
            STAGE(kt + 2, slot2);
        }
        const unsigned short* as = LB[kt & 3][0];
        const unsigned short* bs = LB[kt & 3][1];
        v8s af[8], bf[4];
#pragma unroll
        for (int i = 0; i < 8; i++)
            af[i] = *(const v8s*)&as[(wm * 128 + i * 16 + mrow) * 32 + swr];
#pragma unroll
        for (int j = 0; j < 4; j++)
            bf[j] = *(const v8s*)&bs[(wn * 64 + j * 16 + mrow) * 32 + swr];
        __builtin_amdgcn_s_setprio(1);
#pragma unroll
        for (int i = 0; i < 8; i++)
#pragma unroll
            for (int j = 0; j < 4; j++)
                acc[i][j] = __builtin_amdgcn_mfma_f32_16x16x32_bf16(af[i], bf[j], acc[i][j], 0, 0, 0);
        __builtin_amdgcn_s_setprio(0);
    }
#undef STAGE
    // ---------------- epilogue: stage C tile in LDS, stream out coalesced ----------
    __syncthreads();
    unsigned short* CT = &LB[0][0][0];  // 256 rows x 256 cols bf16 = 128KB
    bool doRelu = QKV && (n0 < 1024);
#pragma unroll
    for (int j = 0; j < 4; j++) {
        int col = wn * 64 + j * 16 + mrow;          // tile-local col
        float bv = bias[n0 + col];
        int gr = col >> 3;                           // granule 0..31
        int gb = col & 7;
#pragma unroll
        for (int i = 0; i < 8; i++) {
            int rowb = wm * 128 + i * 16 + kq4 * 4;
#pragma unroll
            for (int r = 0; r < 4; r++) {
                int row = rowb + r;
                float v = acc[i][j][r] + bv;
                if (doRelu) v = fmaxf(v, 0.0f);
                CT[row * 256 + ((gr ^ (row & 7)) << 3) + gb] = f2b(v);
            }
        }
    }
    __syncthreads();
    unsigned short* base;
    if (QKV) {
        int seg = n0 >> 9;
        base = (seg == 0) ? o0 : ((seg == 1) ? o1 : o2);
    } else {
        base = o0;
    }
    int cb = n0 & 511;
#pragma unroll
    for (int p = 0; p < 16; p++) {
        int g = p * 512 + t;
        int row = g >> 5, gl = g & 31;
        int phys = gl ^ (row & 7);
        v8s v = *(const v8s*)&CT[row * 256 + (phys << 3)];
        *(v8s*)&base[(size_t)(m0 + row) * 512 + cb + gl * 8] = v;
    }
}

// ---------------- kv partials: per (bh, chunk of 128 rows), no atomics ----------------
__global__ __launch_bounds__(256) void kv_part(const unsigned short* __restrict__ kbuf,
                                               const unsigned short* __restrict__ vbuf,
                                               float* __restrict__ kvp,
                                               float* __restrict__ ksp) {
    int bh = blockIdx.x;   // 0..63
    int b = bh >> 3, h = bh & 7;
    int nc = blockIdx.y;   // 0..31
    __shared__ __align__(16) unsigned short kb[64 * 64];
    __shared__ __align__(16) unsigned short vb[64 * 64];
    int t = threadIdx.x;
    int dk0 = (t >> 4) * 4;
    int dv0 = (t & 15) * 4;
    float acc[4][4] = {};
    float ks[4] = {};
    int lr = t >> 2, lc = (t & 3) * 16;
    for (int n0 = nc * 128; n0 < nc * 128 + 128; n0 += 64) {
        __syncthreads();
        size_t base = ((size_t)(b * 4096 + n0 + lr)) * 512 + h * 64;
        *(v8s*)&kb[lr * 64 + lc]     = *(const v8s*)&kbuf[base + lc];
        *(v8s*)&kb[lr * 64 + lc + 8] = *(const v8s*)&kbuf[base + lc + 8];
        *(v8s*)&vb[lr * 64 + lc]     = *(const v8s*)&vbuf[base + lc];
        *(v8s*)&vb[lr * 64 + lc + 8] = *(const v8s*)&vbuf[base + lc + 8];
        __syncthreads();
#pragma unroll 4
        for (int nn = 0; nn < 64; nn++) {
            v4s kr = *(const v4s*)&kb[nn * 64 + dk0];
            v4s vr = *(const v4s*)&vb[nn * 64 + dv0];
            float kf[4], vf[4];
#pragma unroll
            for (int i = 0; i < 4; i++) { kf[i] = b2f((unsigned short)kr[i]); vf[i] = b2f((unsigned short)vr[i]); }
#pragma unroll
            for (int i = 0; i < 4; i++) {
#pragma unroll
                for (int j = 0; j < 4; j++) acc[i][j] += kf[i] * vf[j];
            }
            if ((t & 15) == 0) {
#pragma unroll
                for (int i = 0; i < 4; i++) ks[i] += kf[i];
            }
        }
    }
    float* dst = kvp + ((size_t)(bh * 32 + nc)) * 4096;
#pragma unroll
    for (int i = 0; i < 4; i++)
        *(float4*)&dst[(dk0 + i) * 64 + dv0] = make_float4(acc[i][0], acc[i][1], acc[i][2], acc[i][3]);
    if ((t & 15) == 0) {
        float* kd = ksp + ((size_t)(bh * 32 + nc)) * 64;
#pragma unroll
        for (int i = 0; i < 4; i++) kd[dk0 + i] = ks[i];
    }
}

// ---------------- kv reduce: sum 32 partials -> kvb, ksum ----------------
__global__ __launch_bounds__(256) void kv_reduce(const float* __restrict__ kvp,
                                                 const float* __restrict__ ksp,
                                                 float* __restrict__ kvb,
                                                 float* __restrict__ ksum) {
    int tid = blockIdx.x * 256 + threadIdx.x;
    int bh = tid >> 12, e = tid & 4095;
    float s = 0.0f;
#pragma unroll 8
    for (int c = 0; c < 32; c++) s += kvp[((size_t)(bh * 32 + c)) * 4096 + e];
    kvb[(size_t)bh * 4096 + e] = s;
    if (tid < 4096) {
        int bh2 = tid >> 6, dk = tid & 63;
        float t = 0.0f;
#pragma unroll 8
        for (int c = 0; c < 32; c++) t += ksp[((size_t)(bh2 * 32 + c)) * 64 + dk];
        ksum[tid] = t;
    }
}

// ---------------- attn; IN-PLACE over q ----------------
__global__ __launch_bounds__(256) void attn_kernel(unsigned short* qa,
                                                   const float* __restrict__ kv,
                                                   const float* __restrict__ ksum) {
    int bh = blockIdx.y;
    int b = bh >> 3, h = bh & 7;
    int nt = blockIdx.x;
    __shared__ float kvs[64 * 64];
    __shared__ float nrm[64];
    int t = threadIdx.x;
    for (int i = t; i < 4096; i += 256) kvs[i] = kv[(size_t)bh * 4096 + i];
    if (t < 64) nrm[t] = fmaxf(ksum[bh * 64 + t], 100.0f);
    __syncthreads();
    int n = nt * 256 + t;
    unsigned short* qp = qa + ((size_t)(b * 4096 + n)) * 512 + h * 64;
    float qf[64];
#pragma unroll
    for (int i = 0; i < 64; i += 8) {
        v8s v = *(const v8s*)&qp[i];
#pragma unroll
        for (int j = 0; j < 8; j++) qf[i + j] = b2f((unsigned short)v[j]);
    }
    float denom = 0.0f;
#pragma unroll
    for (int d = 0; d < 64; d++) denom += qf[d] * nrm[d];
    denom = fmaxf(denom, 100.0f);
    float inv = 1.0f / denom;
#pragma unroll
    for (int dv = 0; dv < 64; dv += 16) {
        float o[16] = {};
        for (int dk = 0; dk < 64; dk++) {
            float q = qf[dk];
#pragma unroll
            for (int i = 0; i < 16; i++) o[i] += q * kvs[dk * 64 + dv + i];
        }
#pragma unroll
        for (int i = 0; i < 16; i++) qp[dv + i] = f2b(o[i] * inv);
    }
}

// ---------------- fused LN2 + transpose: [B,N,C] bf16 -> LN -> [B,C,N] bf16 ----------
__global__ __launch_bounds__(256) void ln2_transpose(const unsigned short* __restrict__ in,
                                                     const float* __restrict__ g,
                                                     const float* __restrict__ bt,
                                                     unsigned short* __restrict__ out) {
    int bid = blockIdx.x;
    int b = bid >> 6;
    int n0 = (bid & 63) * 64;
    __shared__ float gs[512], bs[512];
    __shared__ __align__(16) unsigned short tile[512 * 64];  // [c][n-local], XOR-swizzled
    int t = threadIdx.x;
    for (int i = t; i < 512; i += 256) { gs[i] = g[i]; bs[i] = bt[i]; }
    int nl = t >> 2, sub = t & 3;
    const unsigned short* src = in + ((size_t)(b * 4096 + n0 + nl)) * 512 + sub * 8;
    v8s vv[16];
#pragma unroll
    for (int c16 = 0; c16 < 16; c16++)
        vv[c16] = *(const v8s*)&src[c16 * 32];
    float s = 0.f, s2 = 0.f;
#pragma unroll
    for (int c16 = 0; c16 < 16; c16++)
#pragma unroll
        for (int j = 0; j < 8; j++) {
            float f = b2f((unsigned short)vv[c16][j]);
            s += f; s2 += f * f;
        }
    s += __shfl_xor(s, 1); s2 += __shfl_xor(s2, 1);
    s += __shfl_xor(s, 2); s2 += __shfl_xor(s2, 2);
    float mean = s * (1.f / 512.f);
    float var = s2 * (1.f / 512.f) - mean * mean;
    float inv = rsqrtf(var + 1e-5f);
    __syncthreads();   // gs/bs ready
#pragma unroll
    for (int c16 = 0; c16 < 16; c16++) {
        int cb_ = sub * 8 + c16 * 32;
#pragma unroll
        for (int j = 0; j < 8; j++) {
            int c = cb_ + j;
            float f = b2f((unsigned short)vv[c16][j]);
            float y = (f - mean) * inv * gs[c] + bs[c];
            tile[c * 64 + ((((nl >> 3) ^ (c & 7)) << 3) | (nl & 7))] = f2b(y);
        }
    }
    __syncthreads();
    unsigned short* dst = out + ((size_t)b * 512) * 4096 + n0;
#pragma unroll
    for (int p = 0; p < 16; p++) {
        int chunk = p * 256 + t;
        int c = chunk >> 3, gseg = chunk & 7;
        int phys = gseg ^ (c & 7);
        v8s v = *(const v8s*)&tile[c * 64 + phys * 8];
        *(v8s*)&dst[(size_t)c * 4096 + gseg * 8] = v;
    }
}

// ---------------- depthwise conv 7x7 + GELU + BN stats; column-sliding ----------
__global__ __launch_bounds__(256) void dwconv7_gelu(const unsigned short* __restrict__ in,
                                                    const float* __restrict__ w,
                                                    const float* __restrict__ bias,
                                                    unsigned short* __restrict__ out,
                                                    float* __restrict__ bn_sum,
                                                    float* __restrict__ bn_sumsq) {
    int bc = blockIdx.x;
    int c = bc & 511;
    __shared__ float img[70 * 72];
    __shared__ float wsm[49];
    __shared__ float r1[4], r2[4];
    int t = threadIdx.x;
    int tx = t & 63, ty = t >> 6;
    for (int i = t; i < 70 * 72; i += 256) img[i] = 0.0f;
    if (t < 49) wsm[t] = w[c * 49 + t];
    __syncthreads();
    const unsigned short* src = in + (size_t)bc * 4096;
    for (int p = t; p < 4096; p += 256)
        img[((p >> 6) + 3) * 72 + (p & 63) + 3] = b2f(src[p]);
    __syncthreads();
    float wt[49];
#pragma unroll
    for (int i = 0; i < 49; i++) wt[i] = wsm[i];
    float bv = bias[c];
    float acc[16];
#pragma unroll
    for (int i = 0; i < 16; i++) acc[i] = bv;
    int h0 = ty * 16;
#pragma unroll
    for (int rr = 0; rr < 22; rr++) {
        float v[7];
#pragma unroll
        for (int kw = 0; kw < 7; kw++) v[kw] = img[(h0 + rr) * 72 + tx + kw];
#pragma unroll
        for (int kh = 0; kh < 7; kh++) {
            int o = rr - kh;
            if (o >= 0 && o <= 15) {
                float dot = v[0] * wt[kh * 7];
#pragma unroll
                for (int kw = 1; kw < 7; kw++) dot += v[kw] * wt[kh * 7 + kw];
                acc[o] += dot;
            }
        }
    }
    float s = 0.0f, s2 = 0.0f;
    unsigned short* dst = out + (size_t)bc * 4096;
#pragma unroll
    for (int i = 0; i < 16; i++) {
        float a = acc[i];
        float ge = 0.5f * a * (1.0f + erff(a * 0.70710678118f));
        dst[(h0 + i) * 64 + tx] = f2b(ge);
        s += ge;
        s2 += ge * ge;
    }
    for (int o = 32; o > 0; o >>= 1) {
        s += __shfl_down(s, o);
        s2 += __shfl_down(s2, o);
    }
    int lane = t & 63;
    if (lane == 0) { r1[ty] = s; r2[ty] = s2; }
    __syncthreads();
    if (t == 0) {
        atomicAdd(&bn_sum[c], r1[0] + r1[1] + r1[2] + r1[3]);
        atomicAdd(&bn_sumsq[c], r2[0] + r2[1] + r2[2] + r2[3]);
    }
}

__global__ void bn_finalize(const float* __restrict__ s, const float* __restrict__ s2,
                            const float* __restrict__ g, const float* __restrict__ b,
                            float2* __restrict__ ab) {
    int c = blockIdx.x * blockDim.x + threadIdx.x;
    if (c >= 512) return;
    float m = s[c] * (1.0f / 32768.0f);
    float var = s2[c] * (1.0f / 32768.0f) - m * m;
    float inv = rsqrtf(var + 1e-5f);
    float sc = g[c] * inv;
    ab[c] = make_float2(sc, b[c] - m * sc);
}

// ---------------- depthwise conv 7x7 with BN affine on load; column-sliding -------------------
__global__ __launch_bounds__(256) void dwconv7_bn(const unsigned short* __restrict__ in,
                                                  const float2* __restrict__ bnab,
                                                  const float* __restrict__ w,
                                                  const float* __restrict__ bias,
                                                  unsigned short* __restrict__ out) {
    int bc = blockIdx.x;
    int c = bc & 511;
    __shared__ float img[70 * 72];
    __shared__ float wsm[49];
    int t = threadIdx.x;
    int tx = t & 63, ty = t >> 6;
    for (int i = t; i < 70 * 72; i += 256) img[i] = 0.0f;
    if (t < 49) wsm[t] = w[c * 49 + t];
    __syncthreads();
    float2 ab = bnab[c];
    const unsigned short* src = in + (size_t)bc * 4096;
    for (int p = t; p < 4096; p += 256)
        img[((p >> 6) + 3) * 72 + (p & 63) + 3] = b2f(src[p]) * ab.x + ab.y;
    __syncthreads();
    float wt[49];
#pragma unroll
    for (int i = 0; i < 49; i++) wt[i] = wsm[i];
    float bv = bias[c];
    float acc[16];
#pragma unroll
    for (int i = 0; i < 16; i++) acc[i] = bv;
    int h0 = ty * 16;
#pragma unroll
    for (int rr = 0; rr < 22; rr++) {
        float v[7];
#pragma unroll
        for (int kw = 0; kw < 7; kw++) v[kw] = img[(h0 + rr) * 72 + tx + kw];
#pragma unroll
        for (int kh = 0; kh < 7; kh++) {
            int o = rr - kh;
            if (o >= 0 && o <= 15) {
                float dot = v[0] * wt[kh * 7];
#pragma unroll
                for (int kw = 1; kw < 7; kw++) dot += v[kw] * wt[kh * 7 + kw];
                acc[o] += dot;
            }
        }
    }
    unsigned short* dst = out + (size_t)bc * 4096;
#pragma unroll
    for (int i = 0; i < 16; i++)
        dst[(h0 + i) * 64 + tx] = f2b(acc[i]);
}

// ---------------- final: out = x(f32) + attn(bf16) + y2^T(bf16) -> f32 ----------------
__global__ __launch_bounds__(256) void final_add(const float* __restrict__ x,
                                                 const unsigned short* __restrict__ attn,
                                                 const unsigned short* __restrict__ y2,
                                                 float* __restrict__ out) {
    __shared__ unsigned short tile[32][33];
    int b = blockIdx.z;
    int c0 = blockIdx.x * 32, n0 = blockIdx.y * 32;
    int tx = threadIdx.x, ty = threadIdx.y;
    for (int j = 0; j < 32; j += 8)
        tile[ty + j][tx] = y2[((size_t)(b * 512 + c0 + ty + j)) * 4096 + n0 + tx];
    __syncthreads();
    for (int j = 0; j < 32; j += 8) {
        int n = n0 + ty + j, cc = c0 + tx;
        size_t idx = ((size_t)(b * 4096 + n)) * 512 + cc;
        out[idx] = x[idx] + b2f(attn[idx]) + b2f(tile[tx][ty + j]);
    }
}

// ------------------------------------------------------------------------------------------------
extern "C" void kernel_launch(void* const* d_in, const int* in_sizes, int n_in,
                              void* d_out, int out_size, void* d_ws, size_t ws_size,
                              hipStream_t stream) {
    const float* x     = (const float*)d_in[0];
    const float* qkv_w = (const float*)d_in[1];
    const float* qkv_b = (const float*)d_in[2];
    const float* out_w = (const float*)d_in[3];
    const float* out_b = (const float*)d_in[4];
    const float* pre_g = (const float*)d_in[5];
    const float* pre_b = (const float*)d_in[6];
    const float* lcm_g = (const float*)d_in[7];
    const float* lcm_b = (const float*)d_in[8];
    const float* ci_w  = (const float*)d_in[9];
    const float* ci_b  = (const float*)d_in[10];
    const float* bn_g  = (const float*)d_in[11];
    const float* bn_b  = (const float*)d_in[12];
    const float* co_w  = (const float*)d_in[13];
    const float* co_b  = (const float*)d_in[14];

    char* ws = (char*)d_ws;
    const size_t SLOT = 33554432;  // 32768*512*2 bytes (bf16)
    unsigned short* S0 = (unsigned short*)(ws);               // q -> attn -> xi -> y2
    unsigned short* S1 = (unsigned short*)(ws + SLOT);        // k -> attn_out(bf16)
    unsigned short* S2 = (unsigned short*)(ws + 2 * SLOT);    // v -> y
    const size_t MISC = 3 * SLOT;                             // 96MB
    unsigned short* wT1 = (unsigned short*)(ws + MISC);                 // 1.5MB bf16
    unsigned short* wT2 = (unsigned short*)(ws + MISC + 1572864);       // 0.5MB bf16
    float* kvb          = (float*)(ws + MISC + 2097152);                // 1MB
    float* ksum         = (float*)(ws + MISC + 2097152 + 1048576);      // 16KB
    float* bn_sum       = (float*)(ws + MISC + 2097152 + 1048576 + 16384);        // 2KB
    float* bn_sumsq     = (float*)(ws + MISC + 2097152 + 1048576 + 16384 + 2048); // 2KB
    float2* bnab        = (float2*)(ws + MISC + 3166208);               // 4KB
    float* ksp          = (float*)(ws + MISC + 3170304);                // 512KB
    float* outp         = (float*)d_out;

    // d_out doubles as scratch before final_add fully overwrites it:
    unsigned short* normed = (unsigned short*)d_out;                    // 32MB bf16
    float* kvp             = (float*)((char*)d_out + SLOT);             // 32MB fp32 partials

    dim3 tb(32, 8);
    transpose_f2b<<<dim3(48, 16), tb, 0, stream>>>(qkv_w, wT1, 512, 1536);
    transpose_f2b<<<dim3(16, 16), tb, 0, stream>>>(out_w, wT2, 512, 512);
    zero_fill<<<4, 256, 0, stream>>>(bn_sum, 1024);  // bn_sum + bn_sumsq
    ln_apply<<<32768, 256, 0, stream>>>(x, pre_g, pre_b, normed);
    // M=32768, N=1536 -> 128 x 6 = 768 blocks (768 % 8 == 0)
    gemm256<6, true><<<768, 512, 0, stream>>>(normed, wT1, qkv_b, S0, S1, S2);
    kv_part<<<dim3(64, 32), 256, 0, stream>>>(S1, S2, kvp, ksp);
    kv_reduce<<<1024, 256, 0, stream>>>(kvp, ksp, kvb, ksum);
    attn_kernel<<<dim3(16, 64), 256, 0, stream>>>(S0, kvb, ksum);
    // M=32768, N=512 -> 128 x 2 = 256 blocks (256 % 8 == 0)
    gemm256<2, false><<<256, 512, 0, stream>>>(S0, wT2, out_b, S1, S1, S1);
    // fused LN2 + transpose: S1 [B,N,C] -> S0 [B,C,N]
    ln2_transpose<<<512, 256, 0, stream>>>(S1, lcm_g, lcm_b, S0);
    dwconv7_gelu<<<4096, 256, 0, stream>>>(S0, ci_w, ci_b, S2, bn_sum, bn_sumsq);
    bn_finalize<<<2, 256, 0, stream>>>(bn_sum, bn_sumsq, bn_g, bn_b, bnab);
    dwconv7_bn<<<4096, 256, 0, stream>>>(S2, bnab, co_w, co_b, S0);
    final_add<<<dim3(16, 128, 8), tb, 0, stream>>>(x, S1, S0, outp);
}